// Round 1
// baseline (412.227 us; speedup 1.0000x reference)
//
#include <hip/hip_runtime.h>

#define KK 32
#define HH 6
#define OO 31
#define EPS 1e-6f

// One thread per point p in [0, B*N).
//   mix[o] = sum_k  g*W0 + (-dy/s2)*g*W1 + (-dx/s2)*g*W2
//          + (dy^2/s4 - 1/s2)*g*W3 + (dx*dy/s4)*g*W4 + (dx^2/s4 - 1/s2)*g*W5
//   out[p,o] = mlp[p,o] * mix[o]
// W[k,h,o] is indexed only by loop-uniform indices -> backend scalarizes to
// s_load; inner loop is pure v_fma_f32 with SGPR second operand.
__global__ __launch_bounds__(256) void hermite_fused_kernel(
    const float* __restrict__ mlp,     // [P, OO]
    const float* __restrict__ cd,      // [P, KK, 2]
    const float* __restrict__ sigmas,  // [KK]
    const float* __restrict__ gw,      // [P, KK]
    const float* __restrict__ W,       // [KK, HH, OO]
    float* __restrict__ out,           // [P, OO]
    int P)
{
    __shared__ float s_i2[KK];
    __shared__ float s_i4[KK];

    const int tid = threadIdx.x;
    if (tid < KK) {
        float s = sigmas[tid];
        float s2 = s * s + EPS;
        float s4 = s * s * s * s + EPS;
        s_i2[tid] = 1.0f / s2;
        s_i4[tid] = 1.0f / s4;
    }
    __syncthreads();

    const int p = blockIdx.x * blockDim.x + tid;
    if (p >= P) return;

    float acc[OO];
#pragma unroll
    for (int o = 0; o < OO; ++o) acc[o] = 0.0f;

    const float2* __restrict__ cd2 = (const float2*)cd;
    const size_t pK = (size_t)p * KK;

    for (int k = 0; k < KK; ++k) {
        float2 d = cd2[pK + k];
        float g = gw[pK + k];
        float i2 = s_i2[k];
        float i4 = s_i4[k];

        float dx = d.x, dy = d.y;
        float t2 = g * i2;            // g / s2
        float t4 = g * i4;            // g / s4
        float dxt4 = dx * t4;
        float dyt4 = dy * t4;

        float d0 = g;                 // (0,0)
        float d1 = -dy * t2;          // (0,1)
        float d2 = -dx * t2;          // (1,0)
        float d3 = fmaf(dy, dyt4, -t2); // (0,2): dy^2/s4 - 1/s2, g-folded
        float d4 = dx * dyt4;         // (1,1)
        float d5 = fmaf(dx, dxt4, -t2); // (2,0)

        const float* __restrict__ Wk = W + k * (HH * OO);
#pragma unroll
        for (int o = 0; o < OO; ++o) {
            float a = acc[o];
            a = fmaf(d0, Wk[0 * OO + o], a);
            a = fmaf(d1, Wk[1 * OO + o], a);
            a = fmaf(d2, Wk[2 * OO + o], a);
            a = fmaf(d3, Wk[3 * OO + o], a);
            a = fmaf(d4, Wk[4 * OO + o], a);
            a = fmaf(d5, Wk[5 * OO + o], a);
            acc[o] = a;
        }
    }

    const size_t base = (size_t)p * OO;
#pragma unroll
    for (int o = 0; o < OO; ++o) {
        out[base + o] = mlp[base + o] * acc[o];
    }
}

extern "C" void kernel_launch(void* const* d_in, const int* in_sizes, int n_in,
                              void* d_out, int out_size, void* d_ws, size_t ws_size,
                              hipStream_t stream) {
    const float* mlp    = (const float*)d_in[0]; // [B,N,O]
    const float* cd     = (const float*)d_in[1]; // [B,N,K,2]
    const float* sigmas = (const float*)d_in[2]; // [K]
    const float* gw     = (const float*)d_in[3]; // [B,N,K]
    const float* W      = (const float*)d_in[4]; // [K,H,O]
    float* out          = (float*)d_out;

    const int P = in_sizes[3] / KK; // B*N
    const int block = 256;
    const int grid = (P + block - 1) / block;

    hermite_fused_kernel<<<grid, block, 0, stream>>>(mlp, cd, sigmas, gw, W, out, P);
}

// Round 2
// 215.618 us; speedup vs baseline: 1.9118x; 1.9118x over previous
//
#include <hip/hip_runtime.h>

#define KK 32
#define HH 6
#define OO 31
#define KT 16
#define EPS 1e-6f

// One thread per point. k tiled by 16: cd slice = 8 float4 (2 full 64B
// sectors/lane), gw slice = 4 float4 (1 full sector/lane), loaded back-to-back
// so same-sector misses MSHR-merge -> compulsory HBM traffic only.
// W[k,h,o] indexed wave-uniformly -> s_load, SGPR-operand FMAs.
__global__ __launch_bounds__(256, 4) void hermite_fused_kernel(
    const float* __restrict__ mlp,     // [P, OO]
    const float* __restrict__ cd,      // [P, KK, 2]
    const float* __restrict__ sigmas,  // [KK]
    const float* __restrict__ gw,      // [P, KK]
    const float* __restrict__ W,       // [KK, HH, OO]
    float* __restrict__ out,           // [P, OO]
    int P)
{
    __shared__ float s_i2[KK];
    __shared__ float s_i4[KK];

    const int tid = threadIdx.x;
    if (tid < KK) {
        float s = sigmas[tid];
        s_i2[tid] = 1.0f / (s * s + EPS);
        s_i4[tid] = 1.0f / (s * s * s * s + EPS);
    }
    __syncthreads();

    const int p = blockIdx.x * blockDim.x + tid;
    if (p >= P) return;

    const float4* __restrict__ cdv = (const float4*)(cd + (size_t)p * (KK * 2));
    const float4* __restrict__ gwv = (const float4*)(gw + (size_t)p * KK);

    float acc[OO];
#pragma unroll
    for (int o = 0; o < OO; ++o) acc[o] = 0.0f;

#pragma unroll 1
    for (int kt = 0; kt < KK / KT; ++kt) {
        // Load this tile's cd (16 pairs = 8 float4) and gw (16 = 4 float4)
        // into registers with compile-time lane indices.
        float cf[KT * 2];
        float gf[KT];
#pragma unroll
        for (int i = 0; i < KT / 2; ++i) {
            float4 t = cdv[kt * (KT / 2) + i];
            cf[4 * i + 0] = t.x;
            cf[4 * i + 1] = t.y;
            cf[4 * i + 2] = t.z;
            cf[4 * i + 3] = t.w;
        }
#pragma unroll
        for (int i = 0; i < KT / 4; ++i) {
            float4 t = gwv[kt * (KT / 4) + i];
            gf[4 * i + 0] = t.x;
            gf[4 * i + 1] = t.y;
            gf[4 * i + 2] = t.z;
            gf[4 * i + 3] = t.w;
        }

#pragma unroll
        for (int j = 0; j < KT; ++j) {
            const int k = kt * KT + j;   // uniform across wave (kt rolled, j unrolled)
            float dx = cf[2 * j + 0];
            float dy = cf[2 * j + 1];
            float g  = gf[j];
            float i2 = s_i2[k];
            float i4 = s_i4[k];

            float t2 = g * i2;              // g / s2
            float t4 = g * i4;              // g / s4
            float dxt4 = dx * t4;
            float dyt4 = dy * t4;

            float d0 = g;                    // (0,0)
            float d1 = -dy * t2;             // (0,1)
            float d2 = -dx * t2;             // (1,0)
            float d3 = fmaf(dy, dyt4, -t2);  // (0,2)
            float d4 = dx * dyt4;            // (1,1)
            float d5 = fmaf(dx, dxt4, -t2);  // (2,0)

            const float* __restrict__ Wk = W + k * (HH * OO);
#pragma unroll
            for (int o = 0; o < OO; ++o) {
                float a = acc[o];
                a = fmaf(d0, Wk[0 * OO + o], a);
                a = fmaf(d1, Wk[1 * OO + o], a);
                a = fmaf(d2, Wk[2 * OO + o], a);
                a = fmaf(d3, Wk[3 * OO + o], a);
                a = fmaf(d4, Wk[4 * OO + o], a);
                a = fmaf(d5, Wk[5 * OO + o], a);
                acc[o] = a;
            }
        }
    }

    const size_t base = (size_t)p * OO;
#pragma unroll
    for (int o = 0; o < OO; ++o) {
        out[base + o] = mlp[base + o] * acc[o];
    }
}

extern "C" void kernel_launch(void* const* d_in, const int* in_sizes, int n_in,
                              void* d_out, int out_size, void* d_ws, size_t ws_size,
                              hipStream_t stream) {
    const float* mlp    = (const float*)d_in[0]; // [B,N,O]
    const float* cd     = (const float*)d_in[1]; // [B,N,K,2]
    const float* sigmas = (const float*)d_in[2]; // [K]
    const float* gw     = (const float*)d_in[3]; // [B,N,K]
    const float* W      = (const float*)d_in[4]; // [K,H,O]
    float* out          = (float*)d_out;

    const int P = in_sizes[3] / KK; // B*N
    const int block = 256;
    const int grid = (P + block - 1) / block;

    hermite_fused_kernel<<<grid, block, 0, stream>>>(mlp, cd, sigmas, gw, W, out, P);
}